// Round 1
// baseline (719.872 us; speedup 1.0000x reference)
//
#include <hip/hip_runtime.h>

#define TOKENS 16384
#define DDIM 4096
#define RANK 32
#define TOPK 8

// ---------------- K1: y[t][r] = sum_d x[t][d] * A[r][d] ----------------
// grid (TOKENS/64, NDB), block 64. Each block: 64-token tile x 256-dim chunk.
#define NDB 16
#define DBLK (DDIM / NDB) /* 256 */
#define DSUB 64

__global__ __launch_bounds__(64) void k1_proj(const float* __restrict__ x,
                                              const float* __restrict__ A,
                                              float* __restrict__ y) {
  const int lane = threadIdx.x;      // 0..63, owns token t0+lane
  const int t0 = blockIdx.x * 64;
  const int db = blockIdx.y;

  __shared__ float xs[DSUB][65];     // +1 pad: transpose is 2-way banked (free)

  float acc[RANK];
#pragma unroll
  for (int r = 0; r < RANK; ++r) acc[r] = 0.f;

  const int li = lane & 15, lg = lane >> 4;

  for (int sub = 0; sub < DBLK / DSUB; ++sub) {
    const int d0 = db * DBLK + sub * DSUB;
    // stage x[t0..t0+63][d0..d0+63] transposed into xs[d][t], float4 coalesced
#pragma unroll
    for (int jj = 0; jj < 16; ++jj) {
      const int trow = jj * 4 + lg;
      const float4 v = *reinterpret_cast<const float4*>(
          &x[(size_t)(t0 + trow) * DDIM + d0 + li * 4]);
      xs[li * 4 + 0][trow] = v.x;
      xs[li * 4 + 1][trow] = v.y;
      xs[li * 4 + 2][trow] = v.z;
      xs[li * 4 + 3][trow] = v.w;
    }
    __syncthreads();
    // compute: lane-local token column, A at uniform (scalar) addresses
#pragma unroll
    for (int c = 0; c < DSUB / 16; ++c) {
      float xv[16];
#pragma unroll
      for (int k = 0; k < 16; ++k) xv[k] = xs[c * 16 + k][lane];
#pragma unroll
      for (int r = 0; r < RANK; ++r) {
        const float* Ar = &A[(size_t)r * DDIM + d0 + c * 16];
        float s = 0.f;
#pragma unroll
        for (int k = 0; k < 16; ++k) s = fmaf(xv[k], Ar[k], s);
        acc[r] += s;   // two-level accumulation: tighter fp32 error vs np ref
      }
    }
    __syncthreads();
  }

  float* yp = &y[(size_t)(t0 + lane) * RANK];
#pragma unroll
  for (int r = 0; r < RANK; ++r) atomicAdd(&yp[r], acc[r]);
}

// ---------------- K2: bias, |.| top-8, w = 2*y*mask ----------------
__global__ __launch_bounds__(256) void k2_topk(const float* __restrict__ y,
                                               const float* __restrict__ dbias,
                                               float* __restrict__ w) {
  const int t = blockIdx.x * 256 + threadIdx.x;
  const float* yp = &y[(size_t)t * RANK];
  float yv[RANK], ab[RANK];
#pragma unroll
  for (int q = 0; q < RANK / 4; ++q) {
    const float4 v = reinterpret_cast<const float4*>(yp)[q];
    yv[q * 4 + 0] = v.x; yv[q * 4 + 1] = v.y;
    yv[q * 4 + 2] = v.z; yv[q * 4 + 3] = v.w;
  }
#pragma unroll
  for (int r = 0; r < RANK; ++r) ab[r] = fabsf(yv[r] + dbias[r]);

  unsigned mask = 0;
#pragma unroll
  for (int k = 0; k < TOPK; ++k) {
    float best = -1.f;
    int bi = 0;
#pragma unroll
    for (int r = 0; r < RANK; ++r) {
      // strict > keeps lowest index on ties == jax.lax.top_k stability
      const bool sel = (((mask >> r) & 1u) == 0u) && (ab[r] > best);
      best = sel ? ab[r] : best;
      bi = sel ? r : bi;
    }
    mask |= 1u << bi;
  }

  float* wp = &w[(size_t)t * RANK];
#pragma unroll
  for (int q = 0; q < RANK / 4; ++q) {
    float4 o;
    o.x = ((mask >> (q * 4 + 0)) & 1u) ? 2.0f * yv[q * 4 + 0] : 0.f;
    o.y = ((mask >> (q * 4 + 1)) & 1u) ? 2.0f * yv[q * 4 + 1] : 0.f;
    o.z = ((mask >> (q * 4 + 2)) & 1u) ? 2.0f * yv[q * 4 + 2] : 0.f;
    o.w = ((mask >> (q * 4 + 3)) & 1u) ? 2.0f * yv[q * 4 + 3] : 0.f;
    reinterpret_cast<float4*>(wp)[q] = o;
  }
}

// ---------------- K3: out[t][o] = sum_r w[t][r] * B[o][r] ----------------
// grid (DDIM/512, TOKENS/TCHUNK), block 256; each lane owns 2 output columns.
#define TCHUNK 64

__global__ __launch_bounds__(256) void k3_out(const float* __restrict__ w,
                                              const float* __restrict__ B,
                                              float* __restrict__ out) {
  const int tid = threadIdx.x;
  const int c0 = blockIdx.x * 512 + tid * 2;
  const int tbase = blockIdx.y * TCHUNK;

  float b0[RANK], b1[RANK];
#pragma unroll
  for (int q = 0; q < RANK / 4; ++q) {
    const float4 v0 = reinterpret_cast<const float4*>(&B[(size_t)c0 * RANK])[q];
    const float4 v1 =
        reinterpret_cast<const float4*>(&B[(size_t)(c0 + 1) * RANK])[q];
    b0[q * 4 + 0] = v0.x; b0[q * 4 + 1] = v0.y;
    b0[q * 4 + 2] = v0.z; b0[q * 4 + 3] = v0.w;
    b1[q * 4 + 0] = v1.x; b1[q * 4 + 1] = v1.y;
    b1[q * 4 + 2] = v1.z; b1[q * 4 + 3] = v1.w;
  }

#pragma unroll 2
  for (int tt = 0; tt < TCHUNK; ++tt) {
    const int t = tbase + tt;
    const float* wp = &w[(size_t)t * RANK];  // uniform address -> scalar loads
    float s0 = 0.f, s1 = 0.f;
#pragma unroll
    for (int r = 0; r < RANK; ++r) {
      const float wv = wp[r];
      s0 = fmaf(wv, b0[r], s0);
      s1 = fmaf(wv, b1[r], s1);
    }
    float2 o;
    o.x = s0;
    o.y = s1;
    *reinterpret_cast<float2*>(&out[(size_t)t * DDIM + c0]) = o;
  }
}

extern "C" void kernel_launch(void* const* d_in, const int* in_sizes, int n_in,
                              void* d_out, int out_size, void* d_ws,
                              size_t ws_size, hipStream_t stream) {
  const float* x = (const float*)d_in[0];
  const float* A = (const float*)d_in[1];
  const float* B = (const float*)d_in[2];
  const float* dbias = (const float*)d_in[3];
  float* out = (float*)d_out;

  float* y = (float*)d_ws;                    // TOKENS*RANK floats = 2 MB
  float* w = y + (size_t)TOKENS * RANK;       // next 2 MB

  // y is accumulated with atomics -> must be zeroed every call (replay-safe)
  hipMemsetAsync(y, 0, (size_t)TOKENS * RANK * sizeof(float), stream);

  k1_proj<<<dim3(TOKENS / 64, NDB), 64, 0, stream>>>(x, A, y);
  k2_topk<<<TOKENS / 256, 256, 0, stream>>>(y, dbias, w);
  k3_out<<<dim3(DDIM / 512, TOKENS / TCHUNK), 256, 0, stream>>>(w, B, out);
}

// Round 2
// 429.046 us; speedup vs baseline: 1.6778x; 1.6778x over previous
//
#include <hip/hip_runtime.h>

#define TOKENS 16384
#define DDIM 4096
#define RANK 32
#define TOPK 8
#define DSUB 64

// ---------------- K1: y_part[db][t][r] = sum_{d in chunk db} x[t][d]*A[r][d]
// grid (TOKENS/64, ndb), block 256 (4 waves). Block: 64-token tile; per sub,
// stage a 64x64 x-subtile into swizzled LDS; wave w computes ranks w*8..w*8+7.
__global__ __launch_bounds__(256) void k1_proj(const float* __restrict__ x,
                                               const float* __restrict__ A,
                                               float* __restrict__ y_part) {
  const int tid = threadIdx.x;
  const int lane = tid & 63;        // token owned in compute phase
  const int wid = tid >> 6;         // 0..3 -> rank group
  const int r0 = wid * 8;
  const int t0 = blockIdx.x * 64;
  const int db = blockIdx.y;
  const int dblk = DDIM / gridDim.y;
  const int nsub = dblk / DSUB;

  // [k4][token][4] float4-tiles, token index XOR-swizzled by (k4<<2):
  // both ds_write_b128 (staging) and ds_read_b128 (compute) hit 2 lanes/slot.
  __shared__ float xs[16 * 64 * 4];   // 16 KB

  float acc[8];
#pragma unroll
  for (int r = 0; r < 8; ++r) acc[r] = 0.f;

  const int li = tid & 15;   // dim-group (k4) for staging
  const int th = tid >> 4;   // 0..15

  for (int sub = 0; sub < nsub; ++sub) {
    const int d0 = db * dblk + sub * DSUB;
    // stage: 256 threads x 4 float4 = 64 tokens x 64 dims, coalesced 1KB/instr
#pragma unroll
    for (int jj = 0; jj < 4; ++jj) {
      const int trow = th + jj * 16;
      const float4 v = *reinterpret_cast<const float4*>(
          &x[(size_t)(t0 + trow) * DDIM + d0 + li * 4]);
      *reinterpret_cast<float4*>(&xs[(li * 64 + (trow ^ (li << 2))) * 4]) = v;
    }
    __syncthreads();

#pragma unroll
    for (int c = 0; c < 4; ++c) {
      float xv[16];
#pragma unroll
      for (int j = 0; j < 4; ++j) {
        const int k4 = c * 4 + j;
        const float4 v = *reinterpret_cast<const float4*>(
            &xs[(k4 * 64 + (lane ^ (k4 << 2))) * 4]);
        xv[j * 4 + 0] = v.x; xv[j * 4 + 1] = v.y;
        xv[j * 4 + 2] = v.z; xv[j * 4 + 3] = v.w;
      }
      // A addresses are wave-uniform -> scalar loads; only 8 ranks per wave
      // keeps the in-flight SGPR set small enough to pipeline.
#pragma unroll
      for (int r = 0; r < 8; ++r) {
        const float* Ar = &A[(size_t)(r0 + r) * DDIM + d0 + c * 16];
        float s = 0.f;
#pragma unroll
        for (int k = 0; k < 16; ++k) s = fmaf(xv[k], Ar[k], s);
        acc[r] += s;   // two-level fp32 accumulation (tight vs np reference)
      }
    }
    __syncthreads();
  }

  float* yp = &y_part[((size_t)db * TOKENS + t0 + lane) * RANK + r0];
  float4 o0 = {acc[0], acc[1], acc[2], acc[3]};
  float4 o1 = {acc[4], acc[5], acc[6], acc[7]};
  reinterpret_cast<float4*>(yp)[0] = o0;
  reinterpret_cast<float4*>(yp)[1] = o1;
}

// ---------------- K2: reduce partials, bias, |.| top-8, w = 2*y*mask -------
__global__ __launch_bounds__(256) void k2_topk(const float* __restrict__ y_part,
                                               const float* __restrict__ dbias,
                                               float* __restrict__ w, int ndb) {
  const int t = blockIdx.x * 256 + threadIdx.x;
  float yv[RANK];
#pragma unroll
  for (int r = 0; r < RANK; ++r) yv[r] = 0.f;
  for (int c = 0; c < ndb; ++c) {
    const float* yp = &y_part[((size_t)c * TOKENS + t) * RANK];
#pragma unroll
    for (int q = 0; q < RANK / 4; ++q) {
      const float4 v = reinterpret_cast<const float4*>(yp)[q];
      yv[q * 4 + 0] += v.x; yv[q * 4 + 1] += v.y;
      yv[q * 4 + 2] += v.z; yv[q * 4 + 3] += v.w;
    }
  }

  float ab[RANK];
#pragma unroll
  for (int r = 0; r < RANK; ++r) ab[r] = fabsf(yv[r] + dbias[r]);

  unsigned mask = 0;
#pragma unroll
  for (int k = 0; k < TOPK; ++k) {
    float best = -1.f;
    int bi = 0;
#pragma unroll
    for (int r = 0; r < RANK; ++r) {
      // strict > keeps lowest index on ties == jax.lax.top_k stability
      const bool sel = (((mask >> r) & 1u) == 0u) && (ab[r] > best);
      best = sel ? ab[r] : best;
      bi = sel ? r : bi;
    }
    mask |= 1u << bi;
  }

  float* wp = &w[(size_t)t * RANK];
#pragma unroll
  for (int q = 0; q < RANK / 4; ++q) {
    float4 o;
    o.x = ((mask >> (q * 4 + 0)) & 1u) ? 2.0f * yv[q * 4 + 0] : 0.f;
    o.y = ((mask >> (q * 4 + 1)) & 1u) ? 2.0f * yv[q * 4 + 1] : 0.f;
    o.z = ((mask >> (q * 4 + 2)) & 1u) ? 2.0f * yv[q * 4 + 2] : 0.f;
    o.w = ((mask >> (q * 4 + 3)) & 1u) ? 2.0f * yv[q * 4 + 3] : 0.f;
    reinterpret_cast<float4*>(wp)[q] = o;
  }
}

// ---------------- K3: out[t][o] = sum_r w[t][r] * B[o][r] ----------------
#define TCHUNK 64

__global__ __launch_bounds__(256) void k3_out(const float* __restrict__ w,
                                              const float* __restrict__ B,
                                              float* __restrict__ out) {
  const int tid = threadIdx.x;
  const int c0 = blockIdx.x * 512 + tid * 2;
  const int tbase = blockIdx.y * TCHUNK;

  float b0[RANK], b1[RANK];
#pragma unroll
  for (int q = 0; q < RANK / 4; ++q) {
    const float4 v0 = reinterpret_cast<const float4*>(&B[(size_t)c0 * RANK])[q];
    const float4 v1 =
        reinterpret_cast<const float4*>(&B[(size_t)(c0 + 1) * RANK])[q];
    b0[q * 4 + 0] = v0.x; b0[q * 4 + 1] = v0.y;
    b0[q * 4 + 2] = v0.z; b0[q * 4 + 3] = v0.w;
    b1[q * 4 + 0] = v1.x; b1[q * 4 + 1] = v1.y;
    b1[q * 4 + 2] = v1.z; b1[q * 4 + 3] = v1.w;
  }

#pragma unroll 2
  for (int tt = 0; tt < TCHUNK; ++tt) {
    const int t = tbase + tt;
    const float* wp = &w[(size_t)t * RANK];  // uniform address -> scalar loads
    float s0 = 0.f, s1 = 0.f;
#pragma unroll
    for (int r = 0; r < RANK; ++r) {
      const float wv = wp[r];
      s0 = fmaf(wv, b0[r], s0);
      s1 = fmaf(wv, b1[r], s1);
    }
    float2 o;
    o.x = s0;
    o.y = s1;
    *reinterpret_cast<float2*>(&out[(size_t)t * DDIM + c0]) = o;
  }
}

extern "C" void kernel_launch(void* const* d_in, const int* in_sizes, int n_in,
                              void* d_out, int out_size, void* d_ws,
                              size_t ws_size, hipStream_t stream) {
  const float* x = (const float*)d_in[0];
  const float* A = (const float*)d_in[1];
  const float* B = (const float*)d_in[2];
  const float* dbias = (const float*)d_in[3];
  float* out = (float*)d_out;

  const size_t plane = (size_t)TOKENS * RANK;  // 512K floats = 2 MB
  int ndb = 8;
  while (ndb > 1 && ws_size < (size_t)(ndb + 1) * plane * sizeof(float))
    ndb >>= 1;

  float* y_part = (float*)d_ws;               // ndb planes
  float* w = y_part + (size_t)ndb * plane;    // 1 plane

  k1_proj<<<dim3(TOKENS / 64, ndb), 256, 0, stream>>>(x, A, y_part);
  k2_topk<<<TOKENS / 256, 256, 0, stream>>>(y_part, dbias, w, ndb);
  k3_out<<<dim3(DDIM / 512, TOKENS / TCHUNK), 256, 0, stream>>>(w, B, out);
}

// Round 3
// 283.784 us; speedup vs baseline: 2.5367x; 1.5119x over previous
//
#include <hip/hip_runtime.h>

#define TOKENS 16384
#define DDIM 4096
#define RANK 32
#define TOPK 8
#define DSUB 64

// ---------------- K1: y_part[db][t][r] = sum_{d in chunk db} x[t][d]*A[r][d]
// grid (TOKENS/64, ndb), block 256 (4 waves). Block: 64-token tile; per sub,
// stage a 64x64 x-subtile into swizzled LDS; wave w computes ranks w*8..w*8+7.
// A addresses are wave-uniform (readfirstlane'd wid) -> s_load on scalar pipe.
__global__ __launch_bounds__(256) void k1_proj(const float* __restrict__ x,
                                               const float* __restrict__ A,
                                               float* __restrict__ y_part) {
  const int tid = threadIdx.x;
  const int lane = tid & 63;        // token owned in compute phase
  // tid>>6 is wave-uniform; readfirstlane makes it PROVABLY uniform so the
  // A-load addresses below select the scalar (SMEM) path, not 64-lane VMEM.
  const int wid = __builtin_amdgcn_readfirstlane(tid >> 6);
  const int r0 = wid * 8;
  const int t0 = blockIdx.x * 64;
  const int db = blockIdx.y;
  const int dblk = DDIM / gridDim.y;
  const int nsub = dblk / DSUB;

  // [k4][token][4] float4-tiles, token index XOR-swizzled by (k4<<2):
  // both ds_write_b128 (staging) and ds_read_b128 (compute) hit 2 lanes/slot.
  __shared__ float xs[16 * 64 * 4];   // 16 KB

  float acc[8];
#pragma unroll
  for (int r = 0; r < 8; ++r) acc[r] = 0.f;

  const int li = tid & 15;   // dim-group (k4) for staging
  const int th = tid >> 4;   // 0..15

  for (int sub = 0; sub < nsub; ++sub) {
    const int d0 = db * dblk + sub * DSUB;
    // stage: 256 threads x 4 float4 = 64 tokens x 64 dims, coalesced 1KB/instr
#pragma unroll
    for (int jj = 0; jj < 4; ++jj) {
      const int trow = th + jj * 16;
      const float4 v = *reinterpret_cast<const float4*>(
          &x[(size_t)(t0 + trow) * DDIM + d0 + li * 4]);
      *reinterpret_cast<float4*>(&xs[(li * 64 + (trow ^ (li << 2))) * 4]) = v;
    }
    __syncthreads();

#pragma unroll
    for (int c = 0; c < 4; ++c) {
      float xv[16];
#pragma unroll
      for (int j = 0; j < 4; ++j) {
        const int k4 = c * 4 + j;
        const float4 v = *reinterpret_cast<const float4*>(
            &xs[(k4 * 64 + (lane ^ (k4 << 2))) * 4]);
        xv[j * 4 + 0] = v.x; xv[j * 4 + 1] = v.y;
        xv[j * 4 + 2] = v.z; xv[j * 4 + 3] = v.w;
      }
      // Uniform address -> s_load_dwordx16 per rank; rank-outer keeps the
      // live SGPR window ~2 ranks so the scalar pipe stays ahead of VALU.
#pragma unroll
      for (int r = 0; r < 8; ++r) {
        const float* Ar = &A[(size_t)(r0 + r) * DDIM + d0 + c * 16];
        float s = 0.f;
#pragma unroll
        for (int k = 0; k < 16; ++k) s = fmaf(xv[k], Ar[k], s);
        acc[r] += s;   // two-level fp32 accumulation (tight vs np reference)
      }
    }
    __syncthreads();
  }

  float* yp = &y_part[((size_t)db * TOKENS + t0 + lane) * RANK + r0];
  float4 o0 = {acc[0], acc[1], acc[2], acc[3]};
  float4 o1 = {acc[4], acc[5], acc[6], acc[7]};
  reinterpret_cast<float4*>(yp)[0] = o0;
  reinterpret_cast<float4*>(yp)[1] = o1;
}

// ---------------- K2: reduce partials, bias, |.| top-8, w = 2*y*mask -------
__global__ __launch_bounds__(256) void k2_topk(const float* __restrict__ y_part,
                                               const float* __restrict__ dbias,
                                               float* __restrict__ w, int ndb) {
  const int t = blockIdx.x * 256 + threadIdx.x;
  float yv[RANK];
#pragma unroll
  for (int r = 0; r < RANK; ++r) yv[r] = 0.f;
  for (int c = 0; c < ndb; ++c) {
    const float* yp = &y_part[((size_t)c * TOKENS + t) * RANK];
#pragma unroll
    for (int q = 0; q < RANK / 4; ++q) {
      const float4 v = reinterpret_cast<const float4*>(yp)[q];
      yv[q * 4 + 0] += v.x; yv[q * 4 + 1] += v.y;
      yv[q * 4 + 2] += v.z; yv[q * 4 + 3] += v.w;
    }
  }

  float ab[RANK];
#pragma unroll
  for (int r = 0; r < RANK; ++r) ab[r] = fabsf(yv[r] + dbias[r]);

  unsigned mask = 0;
#pragma unroll
  for (int k = 0; k < TOPK; ++k) {
    float best = -1.f;
    int bi = 0;
#pragma unroll
    for (int r = 0; r < RANK; ++r) {
      // strict > keeps lowest index on ties == jax.lax.top_k stability
      const bool sel = (((mask >> r) & 1u) == 0u) && (ab[r] > best);
      best = sel ? ab[r] : best;
      bi = sel ? r : bi;
    }
    mask |= 1u << bi;
  }

  float* wp = &w[(size_t)t * RANK];
#pragma unroll
  for (int q = 0; q < RANK / 4; ++q) {
    float4 o;
    o.x = ((mask >> (q * 4 + 0)) & 1u) ? 2.0f * yv[q * 4 + 0] : 0.f;
    o.y = ((mask >> (q * 4 + 1)) & 1u) ? 2.0f * yv[q * 4 + 1] : 0.f;
    o.z = ((mask >> (q * 4 + 2)) & 1u) ? 2.0f * yv[q * 4 + 2] : 0.f;
    o.w = ((mask >> (q * 4 + 3)) & 1u) ? 2.0f * yv[q * 4 + 3] : 0.f;
    reinterpret_cast<float4*>(wp)[q] = o;
  }
}

// ---------------- K3: out[t][o] = sum_r w[t][r] * B[o][r] ----------------
#define TCHUNK 64

__global__ __launch_bounds__(256) void k3_out(const float* __restrict__ w,
                                              const float* __restrict__ B,
                                              float* __restrict__ out) {
  const int tid = threadIdx.x;
  const int c0 = blockIdx.x * 512 + tid * 2;
  const int tbase = blockIdx.y * TCHUNK;

  float b0[RANK], b1[RANK];
#pragma unroll
  for (int q = 0; q < RANK / 4; ++q) {
    const float4 v0 = reinterpret_cast<const float4*>(&B[(size_t)c0 * RANK])[q];
    const float4 v1 =
        reinterpret_cast<const float4*>(&B[(size_t)(c0 + 1) * RANK])[q];
    b0[q * 4 + 0] = v0.x; b0[q * 4 + 1] = v0.y;
    b0[q * 4 + 2] = v0.z; b0[q * 4 + 3] = v0.w;
    b1[q * 4 + 0] = v1.x; b1[q * 4 + 1] = v1.y;
    b1[q * 4 + 2] = v1.z; b1[q * 4 + 3] = v1.w;
  }

#pragma unroll 2
  for (int tt = 0; tt < TCHUNK; ++tt) {
    const int t = tbase + tt;
    const float* wp = &w[(size_t)t * RANK];  // uniform address -> scalar loads
    float s0 = 0.f, s1 = 0.f;
#pragma unroll
    for (int r = 0; r < RANK; ++r) {
      const float wv = wp[r];
      s0 = fmaf(wv, b0[r], s0);
      s1 = fmaf(wv, b1[r], s1);
    }
    float2 o;
    o.x = s0;
    o.y = s1;
    *reinterpret_cast<float2*>(&out[(size_t)t * DDIM + c0]) = o;
  }
}

extern "C" void kernel_launch(void* const* d_in, const int* in_sizes, int n_in,
                              void* d_out, int out_size, void* d_ws,
                              size_t ws_size, hipStream_t stream) {
  const float* x = (const float*)d_in[0];
  const float* A = (const float*)d_in[1];
  const float* B = (const float*)d_in[2];
  const float* dbias = (const float*)d_in[3];
  float* out = (float*)d_out;

  const size_t plane = (size_t)TOKENS * RANK;  // 512K floats = 2 MB
  int ndb = 8;
  while (ndb > 1 && ws_size < (size_t)(ndb + 1) * plane * sizeof(float))
    ndb >>= 1;

  float* y_part = (float*)d_ws;               // ndb planes
  float* w = y_part + (size_t)ndb * plane;    // 1 plane

  k1_proj<<<dim3(TOKENS / 64, ndb), 256, 0, stream>>>(x, A, y_part);
  k2_topk<<<TOKENS / 256, 256, 0, stream>>>(y_part, dbias, w, ndb);
  k3_out<<<dim3(DDIM / 512, TOKENS / TCHUNK), 256, 0, stream>>>(w, B, out);
}